// Round 2
// baseline (1476.314 us; speedup 1.0000x reference)
//
#include <hip/hip_runtime.h>
#include <stdint.h>

#define SEQ 1024
#define BATCH 512
#define IN_DIM 128
#define HID 256

typedef _Float16 f16x8 __attribute__((ext_vector_type(8)));
typedef float f32x4 __attribute__((ext_vector_type(4)));

__device__ __forceinline__ uint16_t f2h(float x) {
    _Float16 h = (_Float16)x;
    return __builtin_bit_cast(uint16_t, h);
}

// One block per 2 batch rows, persistent across all SEQ steps.
// 4 waves; wave w owns output columns [w*64, w*64+64) as 4 MFMA col-tiles.
// W_in / W_hh live in VGPRs as MFMA B-fragments (f16). h and x are
// double-buffered in LDS (f16) and consumed as MFMA A-fragments, so the
// all-lanes broadcast of h is done by the matrix pipe, not 96 ds_reads.
__launch_bounds__(256, 1)
__global__ void ctrnn_mfma(const float* __restrict__ x,
                           const float* __restrict__ h0,
                           const float* __restrict__ Win,
                           const float* __restrict__ bin,
                           const float* __restrict__ Whh,
                           const float* __restrict__ bhh,
                           float* __restrict__ out) {
    const int tid  = threadIdx.x;
    const int lane = tid & 63;
    const int w    = tid >> 6;      // wave id 0..3
    const int b0   = blockIdx.x * 2;

    const int lr   = lane & 15;     // col-in-tile (B/C) / row-in-tile (A)
    const int g    = lane >> 4;     // k-group (0..3)
    const int arow = lane & 1;      // A-row source: exact for lanes with (lane&15)<2;
                                    // other lanes feed garbage C rows 2..15 (ignored)

    __shared__ __align__(16) uint16_t HS[2][2][HID];     // [buf][row][k] f16, 2 KB
    __shared__ __align__(16) uint16_t XS[2][2][IN_DIM];  // [buf][row][k] f16, 1 KB

    // ---- B-fragments into registers (one-time; Whh/Win are L2/L3-hot) ----
    // frag element e of (kt,t): W[kt*32 + g*8 + e][w*64 + t*16 + lr]
    f16x8 wh[8][4];   // 128 VGPR
    f16x8 wi[4][4];   //  64 VGPR
#pragma unroll
    for (int kt = 0; kt < 8; kt++)
#pragma unroll
        for (int t = 0; t < 4; t++) {
            const int c = w * 64 + t * 16 + lr;
#pragma unroll
            for (int e = 0; e < 8; e++)
                wh[kt][t][e] = (_Float16)Whh[(kt * 32 + g * 8 + e) * HID + c];
        }
#pragma unroll
    for (int kt = 0; kt < 4; kt++)
#pragma unroll
        for (int t = 0; t < 4; t++) {
            const int c = w * 64 + t * 16 + lr;
#pragma unroll
            for (int e = 0; e < 8; e++)
                wi[kt][t][e] = (_Float16)Win[(kt * 32 + g * 8 + e) * HID + c];
        }

    float bias[4], hc0[4], hc1[4];
#pragma unroll
    for (int t = 0; t < 4; t++) {
        const int c = w * 64 + t * 16 + lr;
        bias[t] = bin[c] + bhh[c];
        hc0[t]  = h0[(b0 + 0) * HID + c];
        hc1[t]  = h0[(b0 + 1) * HID + c];
    }

    // ---- init h buffer 0, stage x[0], prefetch x[1], x[2] ----
    HS[0][0][tid] = f2h(h0[(b0 + 0) * HID + tid]);
    HS[0][1][tid] = f2h(h0[(b0 + 1) * HID + tid]);
    const int xr = tid >> 7, xc = tid & 127;
    XS[0][xr][xc] = f2h(x[(0 * BATCH + b0 + xr) * IN_DIM + xc]);
    float xv_ready = x[(1 * BATCH + b0 + xr) * IN_DIM + xc];
    float xv_fly   = x[(2 * BATCH + b0 + xr) * IN_DIM + xc];
    __syncthreads();

    for (int s = 0; s < SEQ; s++) {
        const int cur = s & 1;
        const int nxt = cur ^ 1;

        // stage x[s+1]; rotate prefetch queue
        XS[nxt][xr][xc] = f2h(xv_ready);
        xv_ready = xv_fly;
        const int sl = (s + 3 < SEQ) ? (s + 3) : (SEQ - 1);
        xv_fly = x[(sl * BATCH + b0 + xr) * IN_DIM + xc];

        // ---- A-fragments: 8 (h) + 4 (x) ds_read_b128 per lane ----
        f16x8 ah[8], ax[4];
        const uint16_t* hb = &HS[cur][arow][0];
        const uint16_t* xb = &XS[cur][arow][0];
#pragma unroll
        for (int kt = 0; kt < 8; kt++)
            ah[kt] = *(const f16x8*)&hb[kt * 32 + g * 8];
#pragma unroll
        for (int kt = 0; kt < 4; kt++)
            ax[kt] = *(const f16x8*)&xb[kt * 32 + g * 8];

        f32x4 acc[4];
#pragma unroll
        for (int t = 0; t < 4; t++)
            acc[t] = (f32x4){bias[t], bias[t], bias[t], bias[t]};

        // recurrent: h @ W_hh  (K = 256 -> 8 k-tiles)
#pragma unroll
        for (int kt = 0; kt < 8; kt++)
#pragma unroll
            for (int t = 0; t < 4; t++)
                acc[t] = __builtin_amdgcn_mfma_f32_16x16x32_f16(ah[kt], wh[kt][t], acc[t], 0, 0, 0);
        // input: x @ W_in  (K = 128 -> 4 k-tiles)
#pragma unroll
        for (int kt = 0; kt < 4; kt++)
#pragma unroll
            for (int t = 0; t < 4; t++)
                acc[t] = __builtin_amdgcn_mfma_f32_16x16x32_f16(ax[kt], wi[kt][t], acc[t], 0, 0, 0);

        // ---- epilogue: C rows 0,1 live in lanes 0-15, regs 0,1 ----
        float hn0[4], hn1[4];
#pragma unroll
        for (int t = 0; t < 4; t++) {
            hn0[t] = 0.8f * hc0[t] + 0.2f * fmaxf(acc[t][0], 0.0f);
            hn1[t] = 0.8f * hc1[t] + 0.2f * fmaxf(acc[t][1], 0.0f);
            hc0[t] = hn0[t];
            hc1[t] = hn1[t];
        }
        // LDS writes first (must land before the barrier), then global stores
        if (lane < 16) {
#pragma unroll
            for (int t = 0; t < 4; t++) {
                const int c = w * 64 + t * 16 + lr;
                HS[nxt][0][c] = f2h(hn0[t]);
                HS[nxt][1][c] = f2h(hn1[t]);
            }
#pragma unroll
            for (int t = 0; t < 4; t++) {
                const int c = w * 64 + t * 16 + lr;
                out[((size_t)s * BATCH + b0 + 0) * HID + c] = hn0[t];
                out[((size_t)s * BATCH + b0 + 1) * HID + c] = hn1[t];
            }
        }
        __syncthreads();
    }

    // ---- h_last ----
    if (lane < 16) {
        float* hl = out + (size_t)SEQ * BATCH * HID;
#pragma unroll
        for (int t = 0; t < 4; t++) {
            const int c = w * 64 + t * 16 + lr;
            hl[(b0 + 0) * HID + c] = hc0[t];
            hl[(b0 + 1) * HID + c] = hc1[t];
        }
    }
}

extern "C" void kernel_launch(void* const* d_in, const int* in_sizes, int n_in,
                              void* d_out, int out_size, void* d_ws, size_t ws_size,
                              hipStream_t stream) {
    const float* x   = (const float*)d_in[0];  // [SEQ, BATCH, IN]
    const float* h0  = (const float*)d_in[1];  // [BATCH, HID]
    const float* Win = (const float*)d_in[2];  // [IN, HID]
    const float* bin = (const float*)d_in[3];  // [HID]
    const float* Whh = (const float*)d_in[4];  // [HID, HID]
    const float* bhh = (const float*)d_in[5];  // [HID]
    float* out = (float*)d_out;                // [SEQ,BATCH,HID] then [BATCH,HID]

    ctrnn_mfma<<<BATCH / 2, HID, 0, stream>>>(x, h0, Win, bin, Whh, bhh, out);
}

// Round 10
// 1287.648 us; speedup vs baseline: 1.1465x; 1.1465x over previous
//
#include <hip/hip_runtime.h>
#include <stdint.h>

#define SEQ 1024
#define BATCH 512
#define IN_DIM 128
#define HID 256

typedef _Float16 f16x8 __attribute__((ext_vector_type(8)));
typedef float f32x4 __attribute__((ext_vector_type(4)));

__device__ __forceinline__ uint16_t f2h(float x) {
    _Float16 h = (_Float16)x;
    return __builtin_bit_cast(uint16_t, h);
}
__device__ __forceinline__ uint32_t pack2(float a, float b) {
    return (uint32_t)f2h(a) | ((uint32_t)f2h(b) << 16);
}

// One block per 2 batch rows, persistent across all SEQ steps. 4 waves; wave w
// owns output columns [w*64, w*64+64). Weights live in VGPR/AGPR as MFMA
// B-fragments. Critical chain per step is ONLY: barrier -> ds_read h-frags ->
// 32 h-MFMAs -> blend -> LDS write. The x-projection for step s+1 (4 ds_reads
// + 16 MFMAs) runs in the h-frag latency shadow; x staging is dword-packed
// float2 by 128 threads (kills the 5e7 sub-dword bank-conflict cycles).
__launch_bounds__(256, 1)
__global__ void ctrnn_mfma(const float* __restrict__ x,
                           const float* __restrict__ h0,
                           const float* __restrict__ Win,
                           const float* __restrict__ bin,
                           const float* __restrict__ Whh,
                           const float* __restrict__ bhh,
                           float* __restrict__ out) {
    const int tid  = threadIdx.x;
    const int lane = tid & 63;
    const int w    = tid >> 6;      // wave id 0..3
    const int b0   = blockIdx.x * 2;

    const int lr   = lane & 15;     // col-in-tile (B/C) / row-in-tile (A)
    const int g    = lane >> 4;     // k-group (0..3)
    const int arow = lane & 1;      // A-row source (exact for C rows 0,1)

    __shared__ __align__(16) uint16_t HS[2][2][HID];     // [buf][row][k] f16
    __shared__ __align__(16) uint16_t XS[2][2][IN_DIM];  // [buf][row][k] f16

    // ---- B-fragments into registers (one-time) ----
    // frag element e of (kt,t): W[kt*32 + g*8 + e][w*64 + t*16 + lr]
    f16x8 wh[8][4];
    f16x8 wi[4][4];
#pragma unroll
    for (int kt = 0; kt < 8; kt++)
#pragma unroll
        for (int t = 0; t < 4; t++) {
            const int c = w * 64 + t * 16 + lr;
#pragma unroll
            for (int e = 0; e < 8; e++)
                wh[kt][t][e] = (_Float16)Whh[(kt * 32 + g * 8 + e) * HID + c];
        }
#pragma unroll
    for (int kt = 0; kt < 4; kt++)
#pragma unroll
        for (int t = 0; t < 4; t++) {
            const int c = w * 64 + t * 16 + lr;
#pragma unroll
            for (int e = 0; e < 8; e++)
                wi[kt][t][e] = (_Float16)Win[(kt * 32 + g * 8 + e) * HID + c];
        }

    float bias[4], hc0[4], hc1[4];
#pragma unroll
    for (int t = 0; t < 4; t++) {
        const int c = w * 64 + t * 16 + lr;
        bias[t] = bin[c] + bhh[c];
        hc0[t]  = h0[(b0 + 0) * HID + c];
        hc1[t]  = h0[(b0 + 1) * HID + c];
    }

    // ---- init h buffer 0; stage x[0], x[1] as packed dwords; prefetch ----
    HS[0][0][tid] = f2h(h0[(b0 + 0) * HID + tid]);
    HS[0][1][tid] = f2h(h0[(b0 + 1) * HID + tid]);

    const bool stg  = tid < 128;
    const int  srow = (tid >> 6) & 1;   // 0..1 (valid for stg threads)
    const int  sp   = tid & 63;         // float2 pair index 0..63
    float2 xv_ready = {0.f, 0.f}, xv_fly = {0.f, 0.f};
    if (stg) {
        float2 v0 = *(const float2*)&x[((size_t)0 * BATCH + b0 + srow) * IN_DIM + 2 * sp];
        ((uint32_t*)XS)[(0 * 2 + srow) * 64 + sp] = pack2(v0.x, v0.y);
        float2 v1 = *(const float2*)&x[((size_t)1 * BATCH + b0 + srow) * IN_DIM + 2 * sp];
        ((uint32_t*)XS)[(1 * 2 + srow) * 64 + sp] = pack2(v1.x, v1.y);
        xv_ready = *(const float2*)&x[((size_t)2 * BATCH + b0 + srow) * IN_DIM + 2 * sp];
        xv_fly   = *(const float2*)&x[((size_t)3 * BATCH + b0 + srow) * IN_DIM + 2 * sp];
    }
    __syncthreads();

    // ---- prologue: xaccA = bias + x[0] @ W_in ----
    f32x4 xaccA[4], xaccB[4];
    {
        f16x8 ax0[4];
        const uint16_t* xb0 = &XS[0][arow][0];
#pragma unroll
    for (int kt = 0; kt < 4; kt++)
            ax0[kt] = *(const f16x8*)&xb0[kt * 32 + g * 8];
#pragma unroll
        for (int t = 0; t < 4; t++)
            xaccA[t] = (f32x4){bias[t], bias[t], bias[t], bias[t]};
#pragma unroll
        for (int kt = 0; kt < 4; kt++)
#pragma unroll
            for (int t = 0; t < 4; t++)
                xaccA[t] = __builtin_amdgcn_mfma_f32_16x16x32_f16(ax0[kt], wi[kt][t], xaccA[t], 0, 0, 0);
    }
    // RACE FIX (round-3 bug): step 0 overwrites XS[0] with x[2]; without this
    // barrier, waves 0/1 can clobber XS[0] before waves 2/3 finish the
    // prologue ds_reads of x[0] above.
    __syncthreads();

#define STEP(S_, ACC_CUR, ACC_NXT)                                                      \
    {                                                                                   \
        const int s_   = (S_);                                                          \
        const int cur_ = s_ & 1;                                                        \
        const int nxt_ = cur_ ^ 1;                                                      \
        /* x-frags for step s+1 (staged at step s-1; buffer != the one written now) */  \
        f16x8 ax_[4];                                                                   \
        const uint16_t* xb_ = &XS[nxt_][arow][0];                                       \
        _Pragma("unroll")                                                               \
        for (int kt = 0; kt < 4; kt++)                                                  \
            ax_[kt] = *(const f16x8*)&xb_[kt * 32 + g * 8];                             \
        /* h-frags for this step (the chain) */                                         \
        f16x8 ah_[8];                                                                   \
        const uint16_t* hb_ = &HS[cur_][arow][0];                                       \
        _Pragma("unroll")                                                               \
        for (int kt = 0; kt < 8; kt++)                                                  \
            ah_[kt] = *(const f16x8*)&hb_[kt * 32 + g * 8];                             \
        /* stage x[s+2] into XS[s&1]; rotate prefetch queue */                          \
        if (stg) {                                                                      \
            ((uint32_t*)XS)[(cur_ * 2 + srow) * 64 + sp] = pack2(xv_ready.x, xv_ready.y); \
            xv_ready = xv_fly;                                                          \
            const int sl_ = (s_ + 4 < SEQ) ? (s_ + 4) : (SEQ - 1);                      \
            xv_fly = *(const float2*)&x[((size_t)sl_ * BATCH + b0 + srow) * IN_DIM + 2 * sp]; \
        }                                                                               \
        /* next-step input projection: independent of h, fills ds-latency shadow */     \
        _Pragma("unroll")                                                               \
        for (int t = 0; t < 4; t++)                                                     \
            ACC_NXT[t] = (f32x4){bias[t], bias[t], bias[t], bias[t]};                   \
        _Pragma("unroll")                                                               \
        for (int kt = 0; kt < 4; kt++)                                                  \
            _Pragma("unroll")                                                           \
            for (int t = 0; t < 4; t++)                                                 \
                ACC_NXT[t] = __builtin_amdgcn_mfma_f32_16x16x32_f16(ax_[kt], wi[kt][t], ACC_NXT[t], 0, 0, 0); \
        /* recurrent projection: the serial chain */                                    \
        _Pragma("unroll")                                                               \
        for (int kt = 0; kt < 8; kt++)                                                  \
            _Pragma("unroll")                                                           \
            for (int t = 0; t < 4; t++)                                                 \
                ACC_CUR[t] = __builtin_amdgcn_mfma_f32_16x16x32_f16(ah_[kt], wh[kt][t], ACC_CUR[t], 0, 0, 0); \
        /* epilogue: C rows 0,1 live in lanes 0-15, regs 0,1 */                         \
        float hn0_[4], hn1_[4];                                                         \
        _Pragma("unroll")                                                               \
        for (int t = 0; t < 4; t++) {                                                   \
            hn0_[t] = 0.8f * hc0[t] + 0.2f * fmaxf(ACC_CUR[t][0], 0.0f);                \
            hn1_[t] = 0.8f * hc1[t] + 0.2f * fmaxf(ACC_CUR[t][1], 0.0f);                \
            hc0[t] = hn0_[t];                                                           \
            hc1[t] = hn1_[t];                                                           \
        }                                                                               \
        if (lane < 16) {                                                                \
            _Pragma("unroll")                                                           \
            for (int t = 0; t < 4; t++) {                                               \
                const int c_ = w * 64 + t * 16 + lr;                                    \
                HS[nxt_][0][c_] = f2h(hn0_[t]);                                         \
                HS[nxt_][1][c_] = f2h(hn1_[t]);                                         \
            }                                                                           \
            _Pragma("unroll")                                                           \
            for (int t = 0; t < 4; t++) {                                               \
                const int c_ = w * 64 + t * 16 + lr;                                    \
                out[((size_t)s_ * BATCH + b0 + 0) * HID + c_] = hn0_[t];                \
                out[((size_t)s_ * BATCH + b0 + 1) * HID + c_] = hn1_[t];                \
            }                                                                           \
        }                                                                               \
        __syncthreads();                                                                \
    }

    for (int s = 0; s < SEQ; s += 2) {
        STEP(s,     xaccA, xaccB);
        STEP(s + 1, xaccB, xaccA);
    }
#undef STEP

    // ---- h_last ----
    if (lane < 16) {
        float* hl = out + (size_t)SEQ * BATCH * HID;
#pragma unroll
        for (int t = 0; t < 4; t++) {
            const int c = w * 64 + t * 16 + lr;
            hl[(b0 + 0) * HID + c] = hc0[t];
            hl[(b0 + 1) * HID + c] = hc1[t];
        }
    }
}

extern "C" void kernel_launch(void* const* d_in, const int* in_sizes, int n_in,
                              void* d_out, int out_size, void* d_ws, size_t ws_size,
                              hipStream_t stream) {
    const float* x   = (const float*)d_in[0];  // [SEQ, BATCH, IN]
    const float* h0  = (const float*)d_in[1];  // [BATCH, HID]
    const float* Win = (const float*)d_in[2];  // [IN, HID]
    const float* bin = (const float*)d_in[3];  // [HID]
    const float* Whh = (const float*)d_in[4];  // [HID, HID]
    const float* bhh = (const float*)d_in[5];  // [HID]
    float* out = (float*)d_out;                // [SEQ,BATCH,HID] then [BATCH,HID]

    ctrnn_mfma<<<BATCH / 2, HID, 0, stream>>>(x, h0, Win, bin, Whh, bhh, out);
}